// Round 1
// baseline (2663.306 us; speedup 1.0000x reference)
//
#include <hip/hip_runtime.h>

// MessagePassingLayer: N=100000 nodes (dim 64), E=1600000 edges (feat 32), hidden 64.
// out = relu([h || segsum(relu([h[src]||h[tgt]||ef] @ eW1 + eb1) @ eW2 + eb2, tgt)] @ uW1 + ub1) @ uW2 + ub2
//
// Round 1: f32 VALU baseline.
//  - 1 thread per edge/node; hid[64] accumulators in VGPRs.
//  - Weights read with wave-uniform indices -> compiler emits scalar loads (SGPR broadcast).
//  - Edge scatter: per-wave 64x64 LDS transpose (row pad 68) -> one coalesced
//    64-dword atomicAdd row per edge instead of 64 scattered lane-atomics.

#define HID 64

__device__ __forceinline__ void fma_row4(float* __restrict__ hid, const float4 x,
                                         const float* __restrict__ w) {
  // hid[j] += x.{x,y,z,w} * w[{0,1,2,3}*64 + j]
#pragma unroll
  for (int j = 0; j < HID; ++j) {
    float t = fmaf(x.x, w[j], hid[j]);
    t = fmaf(x.y, w[64 + j], t);
    t = fmaf(x.z, w[128 + j], t);
    t = fmaf(x.w, w[192 + j], t);
    hid[j] = t;
  }
}

__global__ __launch_bounds__(256, 2)
void edge_mlp_scatter(const float* __restrict__ h, const int* __restrict__ ei,
                      const float* __restrict__ ef,
                      const float* __restrict__ W1, const float* __restrict__ b1,
                      const float* __restrict__ W2, const float* __restrict__ b2,
                      float* __restrict__ agg, int E) {
  __shared__ float stage[4][64][68];  // row pad 68: breaks 32-way bank conflict on transpose writes

  const int tid = threadIdx.x;
  const int wave = tid >> 6;
  const int lane = tid & 63;
  const long long eg = (long long)blockIdx.x * 256 + tid;
  const bool valid = eg < E;
  const int e = valid ? (int)eg : 0;

  const int src = ei[e];
  const int tgt = ei[E + e];

  float hid[HID];
#pragma unroll
  for (int j = 0; j < HID; ++j) hid[j] = b1[j];

  const float4* __restrict__ xs = (const float4*)(h + (size_t)src * 64);
#pragma unroll 2
  for (int kk = 0; kk < 16; ++kk) {
    const float4 x = xs[kk];
    fma_row4(hid, x, W1 + (size_t)(kk * 4) * 64);
  }
  const float4* __restrict__ xt = (const float4*)(h + (size_t)tgt * 64);
#pragma unroll 2
  for (int kk = 0; kk < 16; ++kk) {
    const float4 x = xt[kk];
    fma_row4(hid, x, W1 + (size_t)(64 + kk * 4) * 64);
  }
  const float4* __restrict__ xe = (const float4*)(ef + (size_t)e * 32);
#pragma unroll 2
  for (int kk = 0; kk < 8; ++kk) {
    const float4 x = xe[kk];
    fma_row4(hid, x, W1 + (size_t)(128 + kk * 4) * 64);
  }

  // layer 2: msg = relu(hid) @ W2 + b2
  float msg[HID];
#pragma unroll
  for (int j = 0; j < HID; ++j) msg[j] = b2[j];
#pragma unroll 2
  for (int k = 0; k < HID; ++k) {
    const float av = fmaxf(hid[k], 0.0f);
    const float* __restrict__ w = W2 + (size_t)k * 64;
#pragma unroll
    for (int j = 0; j < HID; ++j) msg[j] = fmaf(av, w[j], msg[j]);
  }

  // transpose through LDS: thread (wave,lane) owns edge wave_base+lane
#pragma unroll
  for (int j4 = 0; j4 < 16; ++j4) {
    float4 v = make_float4(msg[4 * j4 + 0], msg[4 * j4 + 1], msg[4 * j4 + 2], msg[4 * j4 + 3]);
    *(float4*)&stage[wave][lane][4 * j4] = v;
  }
  __syncthreads();

  // coalesced scatter: one 64-dword contiguous atomic row per edge
  const long long wave_base = (long long)blockIdx.x * 256 + wave * 64;
#pragma unroll 1
  for (int i = 0; i < 64; ++i) {
    if (wave_base + i < E) {
      const int t = __shfl(tgt, i);
      const float v = stage[wave][i][lane];
      atomicAdd(agg + (size_t)t * 64 + lane, v);
    }
  }
}

__global__ __launch_bounds__(256, 2)
void node_update(const float* __restrict__ h, const float* __restrict__ agg,
                 const float* __restrict__ W1, const float* __restrict__ b1,
                 const float* __restrict__ W2, const float* __restrict__ b2,
                 float* __restrict__ out, int N) {
  const long long ng = (long long)blockIdx.x * blockDim.x + threadIdx.x;
  const bool valid = ng < N;
  const int n = valid ? (int)ng : 0;

  float hid[HID];
#pragma unroll
  for (int j = 0; j < HID; ++j) hid[j] = b1[j];

  const float4* __restrict__ xh = (const float4*)(h + (size_t)n * 64);
#pragma unroll 2
  for (int kk = 0; kk < 16; ++kk) {
    const float4 x = xh[kk];
    fma_row4(hid, x, W1 + (size_t)(kk * 4) * 64);
  }
  const float4* __restrict__ xa = (const float4*)(agg + (size_t)n * 64);
#pragma unroll 2
  for (int kk = 0; kk < 16; ++kk) {
    const float4 x = xa[kk];
    fma_row4(hid, x, W1 + (size_t)(64 + kk * 4) * 64);
  }

  float o[HID];
#pragma unroll
  for (int j = 0; j < HID; ++j) o[j] = b2[j];
#pragma unroll 2
  for (int k = 0; k < HID; ++k) {
    const float av = fmaxf(hid[k], 0.0f);
    const float* __restrict__ w = W2 + (size_t)k * 64;
#pragma unroll
    for (int j = 0; j < HID; ++j) o[j] = fmaf(av, w[j], o[j]);
  }

  if (valid) {
    float4* __restrict__ po = (float4*)(out + (size_t)n * 64);
#pragma unroll
    for (int j4 = 0; j4 < 16; ++j4) {
      po[j4] = make_float4(o[4 * j4 + 0], o[4 * j4 + 1], o[4 * j4 + 2], o[4 * j4 + 3]);
    }
  }
}

extern "C" void kernel_launch(void* const* d_in, const int* in_sizes, int n_in,
                              void* d_out, int out_size, void* d_ws, size_t ws_size,
                              hipStream_t stream) {
  const float* h   = (const float*)d_in[0];
  const int*   ei  = (const int*)d_in[1];
  const float* ef  = (const float*)d_in[2];
  const float* eW1 = (const float*)d_in[3];
  const float* eb1 = (const float*)d_in[4];
  const float* eW2 = (const float*)d_in[5];
  const float* eb2 = (const float*)d_in[6];
  const float* uW1 = (const float*)d_in[7];
  const float* ub1 = (const float*)d_in[8];
  const float* uW2 = (const float*)d_in[9];
  const float* ub2 = (const float*)d_in[10];
  float* out = (float*)d_out;

  const int N = in_sizes[0] / 64;   // 100000
  const int E = in_sizes[1] / 2;    // 1600000

  float* agg = (float*)d_ws;        // N*64 f32 = 25.6 MB scratch
  hipMemsetAsync(agg, 0, (size_t)N * 64 * sizeof(float), stream);

  edge_mlp_scatter<<<(E + 255) / 256, 256, 0, stream>>>(h, ei, ef, eW1, eb1, eW2, eb2, agg, E);
  node_update<<<(N + 255) / 256, 256, 0, stream>>>(h, agg, uW1, ub1, uW2, ub2, out, N);
}